// Round 2
// baseline (2044.892 us; speedup 1.0000x reference)
//
#include <hip/hip_runtime.h>

#define Bb 32
#define Tt 64
#define Nn 300
#define Dd 128
#define NC (Nn * Dd)              // 38400 columns per (b,t) row
#define BTND ((size_t)Tt * NC)    // 2457600 elems per batch

// Kernel 1: fused Q[b,t,n] = sum_d src*wt1  and  K[b,t,d] = sum_n wt3*src.
// One block per (b,t); 4 waves; lane covers 2 consecutive d via float2.
__global__ __launch_bounds__(256) void qk_kernel(
        const float* __restrict__ src, const float* __restrict__ wt1,
        const float* __restrict__ wt3, float* __restrict__ Q,
        float* __restrict__ K) {
    __shared__ float wt3_s[Nn];
    __shared__ float kred[4 * Dd];
    const int tid = threadIdx.x;
    const int wave = tid >> 6, lane = tid & 63;
    for (int i = tid; i < Nn; i += 256) wt3_s[i] = wt3[i];
    __syncthreads();
    const int d0 = lane * 2;
    const float2 w1 = *(const float2*)(wt1 + d0);
    const float* sbt = src + (size_t)blockIdx.x * NC;
    float* Qrow = Q + (size_t)blockIdx.x * Nn;
    float kx = 0.f, ky = 0.f;
    for (int n = wave; n < Nn; n += 4) {
        float2 v = *(const float2*)(sbt + n * Dd + d0);
        float q = v.x * w1.x + v.y * w1.y;
        #pragma unroll
        for (int off = 32; off > 0; off >>= 1) q += __shfl_down(q, off, 64);
        if (lane == 0) Qrow[n] = q;
        float w3 = wt3_s[n];
        kx = fmaf(w3, v.x, kx);
        ky = fmaf(w3, v.y, ky);
    }
    kred[wave * Dd + d0] = kx;
    kred[wave * Dd + d0 + 1] = ky;
    __syncthreads();
    if (tid < Dd) {
        float s = kred[tid] + kred[Dd + tid] + kred[2 * Dd + tid] + kred[3 * Dd + tid];
        K[(size_t)blockIdx.x * Dd + tid] = s;
    }
}

// Kernel 2: scores[b,q,k] = sum_d (sum_n Q[b,q,n]*wt2[n,d]) * K[b,k,d].
// One block per (b,q); 128 threads (thread = d for QW phase, = k for score phase).
__global__ __launch_bounds__(128) void score_kernel(
        const float* __restrict__ Q, const float* __restrict__ K,
        const float* __restrict__ wt2, float* __restrict__ scores) {
    __shared__ float qs[Nn];
    __shared__ float qws[Dd];
    const int tid = threadIdx.x;
    const int bq = blockIdx.x;  // b*T + q
    const float* Qrow = Q + (size_t)bq * Nn;
    for (int i = tid; i < Nn; i += 128) qs[i] = Qrow[i];
    __syncthreads();
    float qw = 0.f;
    for (int n = 0; n < Nn; ++n) qw = fmaf(qs[n], wt2[n * Dd + tid], qw);
    qws[tid] = qw;
    __syncthreads();
    if (tid < Tt) {
        const int b = bq >> 6;  // T = 64
        const float* Krow = K + (size_t)(b * Tt + tid) * Dd;
        float s = 0.f;
        for (int d = 0; d < Dd; ++d) s = fmaf(qws[d], Krow[d], s);
        scores[(size_t)bq * Tt + tid] = s;
    }
}

// Kernel 3: softmax over the BATCH axis (axis 0), per (q,k) pair.
__global__ __launch_bounds__(256) void softmax_b_kernel(
        const float* __restrict__ scores, float* __restrict__ att) {
    const int idx = blockIdx.x * 256 + threadIdx.x;  // qk index in [0, T*T)
    float v[Bb];
    float m = -1e30f;
    #pragma unroll
    for (int b = 0; b < Bb; ++b) {
        v[b] = scores[b * (Tt * Tt) + idx];
        m = fmaxf(m, v[b]);
    }
    float sum = 0.f;
    #pragma unroll
    for (int b = 0; b < Bb; ++b) {
        float e = __expf(v[b] - m);
        v[b] = e;
        sum += e;
    }
    const float inv = 1.0f / sum;
    #pragma unroll
    for (int b = 0; b < Bb; ++b) att[b * (Tt * Tt) + idx] = v[b] * inv;
}

// Kernel 4: out[b,a,j] = sum_t (att[b,t,a] + (t==a)) * src[b,t,j].
// Per-batch GEMM: out[64 a][38400 j] = (att+I)^T[64x64] * x[64 t][38400 j].
// 512 threads = 8 waves; wave w owns a-range [8w, 8w+8); lane owns 8
// consecutive j. acc[8][8] = 64 VGPRs; per t: 64 FMA vs 2 ds_read_b128.
// __launch_bounds__(512, 6): 6 waves/EU -> k = 6*4/8 = 3 blocks/CU
// (24 waves, 75% occ). Round-1 lesson: (512,2) meant 1 block/CU -> 21%
// occupancy -> global-latency-bound at 271 us with VALUBusy 29%.
#define MIX_JT 512  // j floats per block: 64 lanes * 8
__global__ __launch_bounds__(512, 6) void mix_kernel(
        const float* __restrict__ src, const float* __restrict__ att,
        float* __restrict__ out) {
    __shared__ float att_s[Tt * Tt];  // [t][a], 16 KB
    const int tid = threadIdx.x;
    const int b = blockIdx.y;
    for (int i = tid; i < Tt * Tt; i += 512) {
        int t = i >> 6, a = i & 63;
        float v = att[(size_t)b * Tt * Tt + i];
        att_s[i] = v + (t == a ? 1.0f : 0.0f);
    }
    __syncthreads();
    const int wave = tid >> 6, lane = tid & 63;
    const int a0 = wave * 8;
    const int j = blockIdx.x * MIX_JT + lane * 8;
    const float* sb = src + (size_t)b * BTND + j;
    float* ob = out + (size_t)b * BTND + j;
    float acc[8][8];
    #pragma unroll
    for (int ai = 0; ai < 8; ++ai)
        #pragma unroll
        for (int jj = 0; jj < 8; ++jj) acc[ai][jj] = 0.f;
    // 1-deep prefetch of the next x row (8 floats/thread); index clamped
    // so the loop body is branch-free.
    float4 x0 = *(const float4*)(sb);
    float4 x1 = *(const float4*)(sb + 4);
    for (int t = 0; t < Tt; ++t) {
        const int tn = (t < Tt - 1) ? t + 1 : t;
        const float4 n0 = *(const float4*)(sb + (size_t)tn * NC);
        const float4 n1 = *(const float4*)(sb + (size_t)tn * NC + 4);
        const float4 av0 = *(const float4*)(att_s + t * Tt + a0);
        const float4 av1 = *(const float4*)(att_s + t * Tt + a0 + 4);
        const float av[8] = {av0.x, av0.y, av0.z, av0.w,
                             av1.x, av1.y, av1.z, av1.w};
        const float xv[8] = {x0.x, x0.y, x0.z, x0.w,
                             x1.x, x1.y, x1.z, x1.w};
        #pragma unroll
        for (int ai = 0; ai < 8; ++ai)
            #pragma unroll
            for (int jj = 0; jj < 8; ++jj)
                acc[ai][jj] = fmaf(av[ai], xv[jj], acc[ai][jj]);
        x0 = n0;
        x1 = n1;
    }
    #pragma unroll
    for (int ai = 0; ai < 8; ++ai) {
        float* orow = ob + (size_t)(a0 + ai) * NC;
        float4 s0 = {acc[ai][0], acc[ai][1], acc[ai][2], acc[ai][3]};
        float4 s1 = {acc[ai][4], acc[ai][5], acc[ai][6], acc[ai][7]};
        *(float4*)(orow) = s0;
        *(float4*)(orow + 4) = s1;
    }
}

extern "C" void kernel_launch(void* const* d_in, const int* in_sizes, int n_in,
                              void* d_out, int out_size, void* d_ws, size_t ws_size,
                              hipStream_t stream) {
    const float* src = (const float*)d_in[0];
    const float* wt1 = (const float*)d_in[1];
    const float* wt2 = (const float*)d_in[2];
    const float* wt3 = (const float*)d_in[3];
    float* out = (float*)d_out;

    float* ws = (float*)d_ws;
    float* Q      = ws;                               // B*T*N  = 614400 floats
    float* K      = Q + (size_t)Bb * Tt * Nn;         // B*T*D  = 262144 floats
    float* scores = K + (size_t)Bb * Tt * Dd;         // B*T*T  = 131072 floats
    float* att    = scores + (size_t)Bb * Tt * Tt;    // B*T*T  = 131072 floats
    // total ws use: ~4.6 MB

    qk_kernel<<<Bb * Tt, 256, 0, stream>>>(src, wt1, wt3, Q, K);
    score_kernel<<<Bb * Tt, 128, 0, stream>>>(Q, K, wt2, scores);
    softmax_b_kernel<<<(Tt * Tt) / 256, 256, 0, stream>>>(scores, att);
    dim3 g4(NC / MIX_JT, Bb);
    mix_kernel<<<g4, 512, 0, stream>>>(src, att, out);
}

// Round 3
// 820.091 us; speedup vs baseline: 2.4935x; 2.4935x over previous
//
#include <hip/hip_runtime.h>

#define Bb 32
#define Tt 64
#define Nn 300
#define Dd 128
#define NC (Nn * Dd)              // 38400 columns per (b,t) row
#define BTND ((size_t)Tt * NC)    // 2457600 elems per batch

// Kernel 1: fused Q[b,t,n] = sum_d src*wt1  and  K[b,t,d] = sum_n wt3*src.
// One block per (b,t); 4 waves = 8 half-wave groups; group g covers row
// n = n0 + g, lane-in-group covers 4 consecutive d (float4, 16 B/lane —
// the coalescing sweet spot; v2 used float2/8 B). Per wave-load = 1 KB
// contiguous. Q-reduce is 5 shfl within the 32-lane group.
__global__ __launch_bounds__(256) void qk_kernel(
        const float* __restrict__ src, const float* __restrict__ wt1,
        const float* __restrict__ wt3, float* __restrict__ Q,
        float* __restrict__ K) {
    __shared__ float wt3_s[Nn];
    __shared__ float kred[8 * Dd];  // 8 half-wave groups x 128 d
    const int tid = threadIdx.x;
    const int grp = tid >> 5;       // 0..7
    const int gl = tid & 31;        // lane within group
    for (int i = tid; i < Nn; i += 256) wt3_s[i] = wt3[i];
    __syncthreads();
    const int d0 = gl * 4;
    const float4 w1 = *(const float4*)(wt1 + d0);
    const float* sbt = src + (size_t)blockIdx.x * NC;
    float* Qrow = Q + (size_t)blockIdx.x * Nn;
    float4 k = {0.f, 0.f, 0.f, 0.f};
    for (int n0 = 0; n0 < Nn; n0 += 8) {
        const int n = n0 + grp;
        if (n < Nn) {  // tail: 300 = 8*37 + 4, groups 4..7 idle on last iter
            float4 v = *(const float4*)(sbt + n * Dd + d0);
            float q = v.x * w1.x + v.y * w1.y + v.z * w1.z + v.w * w1.w;
            #pragma unroll
            for (int off = 16; off > 0; off >>= 1) q += __shfl_down(q, off, 32);
            if (gl == 0) Qrow[n] = q;
            const float w3 = wt3_s[n];
            k.x = fmaf(w3, v.x, k.x);
            k.y = fmaf(w3, v.y, k.y);
            k.z = fmaf(w3, v.z, k.z);
            k.w = fmaf(w3, v.w, k.w);
        }
    }
    *(float4*)(kred + grp * Dd + d0) = k;
    __syncthreads();
    if (tid < Dd) {
        float s = 0.f;
        #pragma unroll
        for (int g = 0; g < 8; ++g) s += kred[g * Dd + tid];
        K[(size_t)blockIdx.x * Dd + tid] = s;
    }
}

// Kernel 2: scores[b,q,k] = sum_d (sum_n Q[b,q,n]*wt2[n,d]) * K[b,k,d].
// One block per (b,q); 128 threads (thread = d for QW phase, = k for score phase).
__global__ __launch_bounds__(128) void score_kernel(
        const float* __restrict__ Q, const float* __restrict__ K,
        const float* __restrict__ wt2, float* __restrict__ scores) {
    __shared__ float qs[Nn];
    __shared__ float qws[Dd];
    const int tid = threadIdx.x;
    const int bq = blockIdx.x;  // b*T + q
    const float* Qrow = Q + (size_t)bq * Nn;
    for (int i = tid; i < Nn; i += 128) qs[i] = Qrow[i];
    __syncthreads();
    float qw = 0.f;
    for (int n = 0; n < Nn; ++n) qw = fmaf(qs[n], wt2[n * Dd + tid], qw);
    qws[tid] = qw;
    __syncthreads();
    if (tid < Tt) {
        const int b = bq >> 6;  // T = 64
        const float* Krow = K + (size_t)(b * Tt + tid) * Dd;
        float s = 0.f;
        for (int d = 0; d < Dd; ++d) s = fmaf(qws[d], Krow[d], s);
        scores[(size_t)bq * Tt + tid] = s;
    }
}

// Kernel 3: softmax over the BATCH axis (axis 0), per (q,k) pair.
// Writes att + I (identity folded here: idx = q*64+k, q==k <=> idx%65==0),
// so mix_kernel consumes (att + I) directly with no fixup.
__global__ __launch_bounds__(256) void softmax_b_kernel(
        const float* __restrict__ scores, float* __restrict__ att) {
    const int idx = blockIdx.x * 256 + threadIdx.x;  // qk index in [0, T*T)
    float v[Bb];
    float m = -1e30f;
    #pragma unroll
    for (int b = 0; b < Bb; ++b) {
        v[b] = scores[b * (Tt * Tt) + idx];
        m = fmaxf(m, v[b]);
    }
    float sum = 0.f;
    #pragma unroll
    for (int b = 0; b < Bb; ++b) {
        float e = __expf(v[b] - m);
        v[b] = e;
        sum += e;
    }
    const float inv = 1.0f / sum;
    const float diag = (idx % 65 == 0) ? 1.0f : 0.0f;
    #pragma unroll
    for (int b = 0; b < Bb; ++b) att[b * (Tt * Tt) + idx] = v[b] * inv + diag;
}

// Kernel 4: out[b,a,j] = sum_t attI[b,t,a] * src[b,t,j]  (attI = att + I).
// Per-batch GEMM: out[64 a][38400 j] = attI^T[64x64] * x[64 t][38400 j].
// v4: att values are WAVE-UNIFORM ([t][a-range of the wave]) -> read them
// through the SCALAR pipe (readfirstlane-forced uniform address => s_load),
// eliminating the LDS broadcast bottleneck of v1 (16 ds_read_b128 per 64
// FMA oversubscribed the CU-shared LDS return bus 4x) with ZERO vector-
// pipe cost. v_fmac_f32 takes one SGPR operand natively.
// 256 thr / 4 waves; wave owns 16 a; lane owns 4 j. acc[16][4] = 64 regs.
// __launch_bounds__(256,4): cap 128 VGPR -> no spill (round-2 lesson:
// (512,6) capped at 85 and spilled acc to scratch -> 6 GB HBM traffic).
#define MIX_JT 256  // j floats per block: 64 lanes * 4
__global__ __launch_bounds__(256, 4) void mix_kernel(
        const float* __restrict__ src, const float* __restrict__ attI,
        float* __restrict__ out) {
    const int tid = threadIdx.x;
    const int b = blockIdx.y;
    const int lane = tid & 63;
    const int a0 = __builtin_amdgcn_readfirstlane((tid >> 6) * 16);
    const int j = blockIdx.x * MIX_JT + lane * 4;
    const float* sb = src + (size_t)b * BTND + j;
    float* ob = out + (size_t)b * BTND + j;
    const float* ab = attI + ((size_t)b << 12) + a0;  // row stride Tt=64
    float acc[16][4];
    #pragma unroll
    for (int ai = 0; ai < 16; ++ai)
        #pragma unroll
        for (int jj = 0; jj < 4; ++jj) acc[ai][jj] = 0.f;
    float4 x = *(const float4*)sb;
    for (int t = 0; t < Tt; ++t) {
        const int tn = (t < Tt - 1) ? t + 1 : t;
        const float4 xn = *(const float4*)(sb + (size_t)tn * NC);
        float av[16];
        #pragma unroll
        for (int i = 0; i < 16; ++i) av[i] = ab[t * Tt + i];  // s_load
        #pragma unroll
        for (int ai = 0; ai < 16; ++ai) {
            acc[ai][0] = fmaf(av[ai], x.x, acc[ai][0]);
            acc[ai][1] = fmaf(av[ai], x.y, acc[ai][1]);
            acc[ai][2] = fmaf(av[ai], x.z, acc[ai][2]);
            acc[ai][3] = fmaf(av[ai], x.w, acc[ai][3]);
        }
        x = xn;
    }
    #pragma unroll
    for (int ai = 0; ai < 16; ++ai) {
        float4 s = {acc[ai][0], acc[ai][1], acc[ai][2], acc[ai][3]};
        *(float4*)(ob + (size_t)(a0 + ai) * NC) = s;
    }
}

extern "C" void kernel_launch(void* const* d_in, const int* in_sizes, int n_in,
                              void* d_out, int out_size, void* d_ws, size_t ws_size,
                              hipStream_t stream) {
    const float* src = (const float*)d_in[0];
    const float* wt1 = (const float*)d_in[1];
    const float* wt2 = (const float*)d_in[2];
    const float* wt3 = (const float*)d_in[3];
    float* out = (float*)d_out;

    float* ws = (float*)d_ws;
    float* Q      = ws;                               // B*T*N  = 614400 floats
    float* K      = Q + (size_t)Bb * Tt * Nn;         // B*T*D  = 262144 floats
    float* scores = K + (size_t)Bb * Tt * Dd;         // B*T*T  = 131072 floats
    float* att    = scores + (size_t)Bb * Tt * Tt;    // B*T*T  = 131072 floats
    // total ws use: ~4.6 MB

    qk_kernel<<<Bb * Tt, 256, 0, stream>>>(src, wt1, wt3, Q, K);
    score_kernel<<<Bb * Tt, 128, 0, stream>>>(Q, K, wt2, scores);
    softmax_b_kernel<<<(Tt * Tt) / 256, 256, 0, stream>>>(scores, att);
    dim3 g4(NC / MIX_JT, Bb);
    mix_kernel<<<g4, 256, 0, stream>>>(src, att, out);
}

// Round 4
// 705.051 us; speedup vs baseline: 2.9003x; 1.1632x over previous
//
#include <hip/hip_runtime.h>

#define Bb 32
#define Tt 64
#define Nn 300
#define Dd 128
#define NC (Nn * Dd)              // 38400 columns per (b,t) row
#define BTND ((size_t)Tt * NC)    // 2457600 elems per batch

// Kernel 1: fused Q[b,t,n] = sum_d src*wt1  and  K[b,t,d] = sum_n wt3*src.
// One block per (b,t); 4 waves = 8 half-wave groups; group g covers row
// n = n0 + g, lane-in-group covers 4 consecutive d (float4, 16 B/lane).
// Per wave-load = 1 KB contiguous; HBM-bound (~50-80 us for 314 MB).
__global__ __launch_bounds__(256) void qk_kernel(
        const float* __restrict__ src, const float* __restrict__ wt1,
        const float* __restrict__ wt3, float* __restrict__ Q,
        float* __restrict__ K) {
    __shared__ float wt3_s[Nn];
    __shared__ float kred[8 * Dd];  // 8 half-wave groups x 128 d
    const int tid = threadIdx.x;
    const int grp = tid >> 5;       // 0..7
    const int gl = tid & 31;        // lane within group
    for (int i = tid; i < Nn; i += 256) wt3_s[i] = wt3[i];
    __syncthreads();
    const int d0 = gl * 4;
    const float4 w1 = *(const float4*)(wt1 + d0);
    const float* sbt = src + (size_t)blockIdx.x * NC;
    float* Qrow = Q + (size_t)blockIdx.x * Nn;
    float4 k = {0.f, 0.f, 0.f, 0.f};
    for (int n0 = 0; n0 < Nn; n0 += 8) {
        const int n = n0 + grp;
        if (n < Nn) {  // tail: 300 = 8*37 + 4, groups 4..7 idle on last iter
            float4 v = *(const float4*)(sbt + n * Dd + d0);
            float q = v.x * w1.x + v.y * w1.y + v.z * w1.z + v.w * w1.w;
            #pragma unroll
            for (int off = 16; off > 0; off >>= 1) q += __shfl_down(q, off, 32);
            if (gl == 0) Qrow[n] = q;
            const float w3 = wt3_s[n];
            k.x = fmaf(w3, v.x, k.x);
            k.y = fmaf(w3, v.y, k.y);
            k.z = fmaf(w3, v.z, k.z);
            k.w = fmaf(w3, v.w, k.w);
        }
    }
    *(float4*)(kred + grp * Dd + d0) = k;
    __syncthreads();
    if (tid < Dd) {
        float s = 0.f;
        #pragma unroll
        for (int g = 0; g < 8; ++g) s += kred[g * Dd + tid];
        K[(size_t)blockIdx.x * Dd + tid] = s;
    }
}

// Kernel 2: scores[b,q,k] = sum_d (sum_n Q[b,q,n]*wt2[n,d]) * K[b,k,d].
// One block per (b,q); 128 threads (thread = d for QW phase, = k for score phase).
__global__ __launch_bounds__(128) void score_kernel(
        const float* __restrict__ Q, const float* __restrict__ K,
        const float* __restrict__ wt2, float* __restrict__ scores) {
    __shared__ float qs[Nn];
    __shared__ float qws[Dd];
    const int tid = threadIdx.x;
    const int bq = blockIdx.x;  // b*T + q
    const float* Qrow = Q + (size_t)bq * Nn;
    for (int i = tid; i < Nn; i += 128) qs[i] = Qrow[i];
    __syncthreads();
    float qw = 0.f;
    for (int n = 0; n < Nn; ++n) qw = fmaf(qs[n], wt2[n * Dd + tid], qw);
    qws[tid] = qw;
    __syncthreads();
    if (tid < Tt) {
        const int b = bq >> 6;  // T = 64
        const float* Krow = K + (size_t)(b * Tt + tid) * Dd;
        float s = 0.f;
        for (int d = 0; d < Dd; ++d) s = fmaf(qws[d], Krow[d], s);
        scores[(size_t)bq * Tt + tid] = s;
    }
}

// Kernel 3: softmax over the BATCH axis (axis 0), per (q,k) pair.
// Writes att + I (identity folded: idx = q*64+k, q==k <=> idx%65==0).
// 64 blocks x 64 threads (was 16 blocks: 94% of CUs idle, latency-exposed).
__global__ __launch_bounds__(64) void softmax_b_kernel(
        const float* __restrict__ scores, float* __restrict__ att) {
    const int idx = blockIdx.x * 64 + threadIdx.x;  // qk index in [0, T*T)
    float v[Bb];
    float m = -1e30f;
    #pragma unroll
    for (int b = 0; b < Bb; ++b) {
        v[b] = scores[b * (Tt * Tt) + idx];
        m = fmaxf(m, v[b]);
    }
    float sum = 0.f;
    #pragma unroll
    for (int b = 0; b < Bb; ++b) {
        float e = __expf(v[b] - m);
        v[b] = e;
        sum += e;
    }
    const float inv = 1.0f / sum;
    const float diag = (idx % 65 == 0) ? 1.0f : 0.0f;
    #pragma unroll
    for (int b = 0; b < Bb; ++b) att[b * (Tt * Tt) + idx] = v[b] * inv + diag;
}

// Kernel 4: out[b,a,j] = sum_t attI[b,t,a] * src[b,t,j]  (attI = att + I).
// 512 thr = 8 waves; wave w owns a in [8w,8w+8); lane owns 8 consecutive j.
// acc[8][8]=64 VGPRs. Per t per wave: 64 FMA vs 2 broadcast ds_read_b128.
// Broadcast b128 measured ~7.5 cyc (round-0 retro-model) -> LDS demand is
// ~25% of VALU issue at this shape: VALU/HBM-bound, not LDS-bound.
// __launch_bounds__(512, 4): k = 4*4/8 = 2 blocks/CU (16 waves, 50% occ),
// VGPR cap 128 (uses ~76-90, no spill).
//   round-1 lesson: (512,2) -> 1 block/CU -> latency-bound, 271 us.
//   round-2 lesson: (512,6) -> cap 85 -> acc spilled to scratch, 1613 us.
//   round-3 lesson: per-iter uniform s_load/global att reads serialize, 340 us.
#define MIX_JT 512  // j floats per block: 64 lanes * 8
__global__ __launch_bounds__(512, 4) void mix_kernel(
        const float* __restrict__ src, const float* __restrict__ attI,
        float* __restrict__ out) {
    __shared__ float att_s[Tt * Tt];  // [t][a], 16 KB
    const int tid = threadIdx.x;
    const int b = blockIdx.y;
    for (int i = tid; i < Tt * Tt; i += 512)
        att_s[i] = attI[(size_t)b * Tt * Tt + i];
    __syncthreads();
    const int wave = tid >> 6, lane = tid & 63;
    const int a0 = wave * 8;
    const int j = blockIdx.x * MIX_JT + lane * 8;
    const float* sb = src + (size_t)b * BTND + j;
    float* ob = out + (size_t)b * BTND + j;
    float acc[8][8];
    #pragma unroll
    for (int ai = 0; ai < 8; ++ai)
        #pragma unroll
        for (int jj = 0; jj < 8; ++jj) acc[ai][jj] = 0.f;
    // 1-deep prefetch of the next x row (8 floats/thread), clamped index.
    float4 x0 = *(const float4*)(sb);
    float4 x1 = *(const float4*)(sb + 4);
    for (int t = 0; t < Tt; ++t) {
        const int tn = (t < Tt - 1) ? t + 1 : t;
        const float4 n0 = *(const float4*)(sb + (size_t)tn * NC);
        const float4 n1 = *(const float4*)(sb + (size_t)tn * NC + 4);
        const float4 av0 = *(const float4*)(att_s + t * Tt + a0);
        const float4 av1 = *(const float4*)(att_s + t * Tt + a0 + 4);
        const float av[8] = {av0.x, av0.y, av0.z, av0.w,
                             av1.x, av1.y, av1.z, av1.w};
        const float xv[8] = {x0.x, x0.y, x0.z, x0.w,
                             x1.x, x1.y, x1.z, x1.w};
        #pragma unroll
        for (int ai = 0; ai < 8; ++ai)
            #pragma unroll
            for (int jj = 0; jj < 8; ++jj)
                acc[ai][jj] = fmaf(av[ai], xv[jj], acc[ai][jj]);
        x0 = n0;
        x1 = n1;
    }
    #pragma unroll
    for (int ai = 0; ai < 8; ++ai) {
        float* orow = ob + (size_t)(a0 + ai) * NC;
        float4 s0 = {acc[ai][0], acc[ai][1], acc[ai][2], acc[ai][3]};
        float4 s1 = {acc[ai][4], acc[ai][5], acc[ai][6], acc[ai][7]};
        *(float4*)(orow) = s0;
        *(float4*)(orow + 4) = s1;
    }
}

extern "C" void kernel_launch(void* const* d_in, const int* in_sizes, int n_in,
                              void* d_out, int out_size, void* d_ws, size_t ws_size,
                              hipStream_t stream) {
    const float* src = (const float*)d_in[0];
    const float* wt1 = (const float*)d_in[1];
    const float* wt2 = (const float*)d_in[2];
    const float* wt3 = (const float*)d_in[3];
    float* out = (float*)d_out;

    float* ws = (float*)d_ws;
    float* Q      = ws;                               // B*T*N  = 614400 floats
    float* K      = Q + (size_t)Bb * Tt * Nn;         // B*T*D  = 262144 floats
    float* scores = K + (size_t)Bb * Tt * Dd;         // B*T*T  = 131072 floats
    float* att    = scores + (size_t)Bb * Tt * Tt;    // B*T*T  = 131072 floats
    // total ws use: ~4.6 MB

    qk_kernel<<<Bb * Tt, 256, 0, stream>>>(src, wt1, wt3, Q, K);
    score_kernel<<<Bb * Tt, 128, 0, stream>>>(Q, K, wt2, scores);
    softmax_b_kernel<<<(Tt * Tt) / 64, 64, 0, stream>>>(scores, att);
    dim3 g4(NC / MIX_JT, Bb);
    mix_kernel<<<g4, 512, 0, stream>>>(src, att, out);
}